// Round 19
// baseline (335.778 us; speedup 1.0000x reference)
//
#include <hip/hip_runtime.h>
#include <math.h>

#define NPOINTS (1 << 21)
#define LVL 16
#define TSIZE (1 << 19)
#define TMASK (TSIZE - 1)
#define PRIME2 2654435761u

// Morton 512x512 (18-bit key). coarse = key>>8 (32x32), fine = key&255 (16x16).
#define GBITS 9
#define GRES (1 << GBITS)
#define SCAN_CHUNK 1024
#define CB 1024                        // coarse bins
#define PPB 8192                       // points per phase-1 block
#define NB1 (NPOINTS / PPB)            // 256 blocks
#define MSIZE (CB * NB1)               // 262144 matrix entries
#define NCHUNKS (MSIZE / SCAN_CHUNK)   // 256
#define CAP 2560                       // fine-sort LDS capacity

typedef float f32x2 __attribute__((ext_vector_type(2)));
typedef float f32x4 __attribute__((ext_vector_type(4)));

struct Params {
    int   n[LVL];
    float fn[LVL];
};

__device__ __forceinline__ unsigned part1by1(unsigned v) {
    v &= 0xFFFFu;
    v = (v | (v << 8)) & 0x00FF00FFu;
    v = (v | (v << 4)) & 0x0F0F0F0Fu;
    v = (v | (v << 2)) & 0x33333333u;
    v = (v | (v << 1)) & 0x55555555u;
    return v;
}

__device__ __forceinline__ unsigned morton_key(f32x2 pt) {
    int kx = (int)(pt.x * (float)GRES);
    int ky = (int)(pt.y * (float)GRES);
    kx = min(max(kx, 0), GRES - 1);
    ky = min(max(ky, 0), GRES - 1);
    return (part1by1((unsigned)ky) << 1) | part1by1((unsigned)kx);
}

// Plain 4-gather bilinear lookup (bit-identical to reference math).
__device__ __forceinline__ f32x2 level_feat(const f32x2* __restrict__ tables,
                                            int l, int N, float fN, f32x2 pt)
{
    float sx = pt.x * fN;
    float sy = pt.y * fN;
    float fx = floorf(sx);
    float fy = floorf(sy);
    float wx = sx - fx;
    float wy = sy - fy;
    int ix = (int)fx;
    int iy = (int)fy;

    int cx0 = (ix     >= N) ? ix - N     : ix;
    int cx1 = (ix + 1 >= N) ? ix + 1 - N : ix + 1;
    int cy0 = (iy     >= N) ? iy - N     : iy;
    int cy1 = (iy + 1 >= N) ? iy + 1 - N : iy + 1;

    unsigned hy0 = (unsigned)cy0 * PRIME2;
    unsigned hy1 = (unsigned)cy1 * PRIME2;

    const f32x2* tbl = tables + (size_t)l * TSIZE;
    f32x2 c00 = tbl[(int)(((unsigned)cx0 ^ hy0) & TMASK)];
    f32x2 c10 = tbl[(int)(((unsigned)cx1 ^ hy0) & TMASK)];
    f32x2 c01 = tbl[(int)(((unsigned)cx0 ^ hy1) & TMASK)];
    f32x2 c11 = tbl[(int)(((unsigned)cx1 ^ hy1) & TMASK)];

    float omx = 1.0f - wx, omy = 1.0f - wy;
    float f0x = c00.x * omx + c10.x * wx;
    float f0y = c00.y * omx + c10.y * wx;
    float f1x = c01.x * omx + c11.x * wx;
    float f1y = c01.y * omx + c11.y * wx;

    f32x2 r;
    r.x = f0x * omy + f1x * wy;
    r.y = f0y * omy + f1y * wy;
    return r;
}

// Pair lookup: full gather for point A; point B reuses A's corners when its
// cell matches (P ~ (1-N/512)^2 after the fine sort), else gathers under
// exec mask (masked-off lanes issue no TA requests -- R8). Same entries,
// same blend order -> bit-identical values.
__device__ __forceinline__ void level_pair(
    const f32x2* __restrict__ tables, int l, int N, float fN,
    f32x2 pa, f32x2 pb, f32x2& ra, f32x2& rb)
{
    const f32x2* tbl = tables + (size_t)l * TSIZE;

    float sxa = pa.x * fN, sya = pa.y * fN;
    float fxa = floorf(sxa), fya = floorf(sya);
    float wxa = sxa - fxa, wya = sya - fya;
    int ixa = (int)fxa, iya = (int)fya;

    int cx0a = (ixa     >= N) ? ixa - N     : ixa;
    int cx1a = (ixa + 1 >= N) ? ixa + 1 - N : ixa + 1;
    int cy0a = (iya     >= N) ? iya - N     : iya;
    int cy1a = (iya + 1 >= N) ? iya + 1 - N : iya + 1;

    unsigned hy0a = (unsigned)cy0a * PRIME2;
    unsigned hy1a = (unsigned)cy1a * PRIME2;
    f32x2 c00 = tbl[(int)(((unsigned)cx0a ^ hy0a) & TMASK)];
    f32x2 c10 = tbl[(int)(((unsigned)cx1a ^ hy0a) & TMASK)];
    f32x2 c01 = tbl[(int)(((unsigned)cx0a ^ hy1a) & TMASK)];
    f32x2 c11 = tbl[(int)(((unsigned)cx1a ^ hy1a) & TMASK)];

    {
        float omx = 1.0f - wxa, omy = 1.0f - wya;
        float f0x = c00.x * omx + c10.x * wxa;
        float f0y = c00.y * omx + c10.y * wxa;
        float f1x = c01.x * omx + c11.x * wxa;
        float f1y = c01.y * omx + c11.y * wxa;
        ra.x = f0x * omy + f1x * wya;
        ra.y = f0y * omy + f1y * wya;
    }

    float sxb = pb.x * fN, syb = pb.y * fN;
    float fxb = floorf(sxb), fyb = floorf(syb);
    float wxb = sxb - fxb, wyb = syb - fyb;
    int ixb = (int)fxb, iyb = (int)fyb;

    f32x2 d00 = c00, d10 = c10, d01 = c01, d11 = c11;
    if (!(ixb == ixa && iyb == iya)) {
        int cx0b = (ixb     >= N) ? ixb - N     : ixb;
        int cx1b = (ixb + 1 >= N) ? ixb + 1 - N : ixb + 1;
        int cy0b = (iyb     >= N) ? iyb - N     : iyb;
        int cy1b = (iyb + 1 >= N) ? iyb + 1 - N : iyb + 1;
        unsigned hy0b = (unsigned)cy0b * PRIME2;
        unsigned hy1b = (unsigned)cy1b * PRIME2;
        d00 = tbl[(int)(((unsigned)cx0b ^ hy0b) & TMASK)];
        d10 = tbl[(int)(((unsigned)cx1b ^ hy0b) & TMASK)];
        d01 = tbl[(int)(((unsigned)cx0b ^ hy1b) & TMASK)];
        d11 = tbl[(int)(((unsigned)cx1b ^ hy1b) & TMASK)];
    }

    {
        float omx = 1.0f - wxb, omy = 1.0f - wyb;
        float f0x = d00.x * omx + d10.x * wxb;
        float f0y = d00.y * omx + d10.y * wxb;
        float f1x = d01.x * omx + d11.x * wxb;
        float f1y = d01.y * omx + d11.y * wxb;
        rb.x = f0x * omy + f1x * wyb;
        rb.y = f0y * omy + f1y * wyb;
    }
}

// ---- Phase A1: per-block coarse histogram -> M[bin][block].
__global__ __launch_bounds__(256) void hist1_kernel(
    const f32x2* __restrict__ xy, unsigned* __restrict__ M)
{
    __shared__ unsigned lh[CB];
    int tid = threadIdx.x, b = blockIdx.x;
    for (int k = tid; k < CB; k += 256) lh[k] = 0;
    __syncthreads();
    int base = b * PPB;
    #pragma unroll
    for (int i = 0; i < PPB / 256; ++i) {
        f32x2 pt = __builtin_nontemporal_load(&xy[base + i * 256 + tid]);
        atomicAdd(&lh[morton_key(pt) >> 8], 1u);
    }
    __syncthreads();
    for (int k = tid; k < CB; k += 256) M[k * NB1 + b] = lh[k];
}

// ---- Scan: exclusive scan of M's 262144 entries (bin, block) order.
__global__ __launch_bounds__(SCAN_CHUNK) void scan_local_kernel(
    unsigned* __restrict__ hist, unsigned* __restrict__ aux)
{
    __shared__ unsigned s[SCAN_CHUNK];
    int t = threadIdx.x;
    int i = blockIdx.x * SCAN_CHUNK + t;
    unsigned v = hist[i];
    s[t] = v;
    __syncthreads();
    #pragma unroll
    for (int o = 1; o < SCAN_CHUNK; o <<= 1) {
        unsigned x = (t >= o) ? s[t - o] : 0u;
        __syncthreads();
        s[t] += x;
        __syncthreads();
    }
    hist[i] = s[t] - v;
    if (t == SCAN_CHUNK - 1) aux[blockIdx.x] = s[t];
}

__global__ __launch_bounds__(NCHUNKS) void scan_aux_kernel(unsigned* __restrict__ aux)
{
    __shared__ unsigned s[NCHUNKS];
    int t = threadIdx.x;
    unsigned v = aux[t];
    s[t] = v;
    __syncthreads();
    #pragma unroll
    for (int o = 1; o < NCHUNKS; o <<= 1) {
        unsigned x = (t >= o) ? s[t - o] : 0u;
        __syncthreads();
        s[t] += x;
        __syncthreads();
    }
    aux[t] = s[t] - v;
}

// ---- Phase A2: aggregated scatter via LDS cursors.
__global__ __launch_bounds__(256) void scatter1_kernel(
    const f32x2* __restrict__ xy, const unsigned* __restrict__ M,
    const unsigned* __restrict__ aux, f32x4* __restrict__ slotsA)
{
    __shared__ unsigned cur[CB];
    int tid = threadIdx.x, b = blockIdx.x;
    for (int k = tid; k < CB; k += 256) {
        unsigned idx = (unsigned)k * NB1 + b;
        cur[k] = M[idx] + aux[idx >> 10];
    }
    __syncthreads();
    int base = b * PPB;
    #pragma unroll
    for (int i = 0; i < PPB / 256; ++i) {
        int p = base + i * 256 + tid;
        f32x2 pt = __builtin_nontemporal_load(&xy[p]);
        unsigned k = morton_key(pt) >> 8;
        unsigned pos = atomicAdd(&cur[k], 1u);
        f32x4 s = { pt.x, pt.y, __uint_as_float((unsigned)p), 0.0f };
        slotsA[pos] = s;
    }
}

// ---- Phase B: per-coarse-bin fine counting sort (LDS).
__global__ __launch_bounds__(256) void fine_kernel(
    const f32x4* __restrict__ slotsA, const unsigned* __restrict__ M,
    const unsigned* __restrict__ aux, f32x4* __restrict__ slotsB)
{
    __shared__ f32x4 buf[CAP];
    __shared__ unsigned fh[256];
    __shared__ unsigned fc[256];

    int tid = threadIdx.x;
    int k   = blockIdx.x;

    unsigned i0 = (unsigned)k * NB1;
    unsigned start = M[i0] + aux[i0 >> 10];
    unsigned end;
    if (k == CB - 1) end = NPOINTS;
    else {
        unsigned i1 = (unsigned)(k + 1) * NB1;
        end = M[i1] + aux[i1 >> 10];
    }
    unsigned n = end - start;
    unsigned m = n > CAP ? CAP : n;

    fh[tid] = 0;
    __syncthreads();
    for (unsigned i = tid; i < m; i += 256) {
        f32x4 s = slotsA[start + i];
        buf[i] = s;
        f32x2 pt = { s.x, s.y };
        atomicAdd(&fh[morton_key(pt) & 255u], 1u);
    }
    __syncthreads();
    unsigned v = fh[tid];
    fc[tid] = v;
    __syncthreads();
    #pragma unroll
    for (int o = 1; o < 256; o <<= 1) {
        unsigned x = (tid >= o) ? fc[tid - o] : 0u;
        __syncthreads();
        fc[tid] += x;
        __syncthreads();
    }
    unsigned excl = fc[tid] - v;
    __syncthreads();
    fc[tid] = excl;
    __syncthreads();
    for (unsigned i = tid; i < m; i += 256) {
        f32x4 s = buf[i];
        f32x2 pt = { s.x, s.y };
        unsigned r = atomicAdd(&fc[morton_key(pt) & 255u], 1u);
        slotsB[start + r] = s;
    }
    for (unsigned i = CAP + tid; i < n; i += 256)
        slotsB[start + i] = slotsA[start + i];
}

// ---- Main: barrier-free streaming (R17 structure) + 2 consecutive points
// per thread with corner reuse. XCD-bijective swizzle over 4096 blocks.
__global__ __launch_bounds__(256) void main_kernel(
    const f32x4* __restrict__ slots,
    const f32x2* __restrict__ tables,
    f32x4* __restrict__ out,
    Params P)
{
    int bid = (blockIdx.x & 7) * 512 + (blockIdx.x >> 3);   // 4096 blocks
    int t   = bid * 256 + threadIdx.x;
    int sp0 = t * 2;

    f32x4 s0 = __builtin_nontemporal_load(&slots[sp0]);
    f32x4 s1 = __builtin_nontemporal_load(&slots[sp0 + 1]);
    f32x2 pa = { s0.x, s0.y };
    f32x2 pb = { s1.x, s1.y };
    unsigned opa = __float_as_uint(s0.z);
    unsigned opb = __float_as_uint(s1.z);
    f32x4* oa = out + (size_t)opa * 8;
    f32x4* ob = out + (size_t)opb * 8;

    #pragma unroll
    for (int hb = 0; hb < 2; ++hb) {
        #pragma unroll
        for (int q = 0; q < 4; ++q) {
            int l = hb * 8 + q * 2;
            f32x2 ra0, rb0, ra1, rb1;
            level_pair(tables, l,     P.n[l],     P.fn[l],     pa, pb, ra0, rb0);
            level_pair(tables, l + 1, P.n[l + 1], P.fn[l + 1], pa, pb, ra1, rb1);
            f32x4 va = { ra0.x, ra0.y, ra1.x, ra1.y };
            f32x4 vb = { rb0.x, rb0.y, rb1.x, rb1.y };
            oa[hb * 4 + q] = va;                 // plain store: L2 merges
            ob[hb * 4 + q] = vb;
        }
    }
}

// ---- Fallback (ws too small): single-pass kernel (~433 us).
__global__ __launch_bounds__(256, 6) void hashgrid2d_fallback(
    const f32x2* __restrict__ xy,
    const f32x2* __restrict__ tables,
    f32x4* __restrict__ out,
    Params P)
{
    __shared__ f32x4 lds[256 * 5];

    int tid = threadIdx.x;
    int p   = blockIdx.x * 256 + tid;

    f32x2 pt = __builtin_nontemporal_load(&xy[p]);
    size_t base = (size_t)blockIdx.x * 2048;

    #pragma unroll
    for (int b = 0; b < 2; ++b) {
        #pragma unroll
        for (int q = 0; q < 4; ++q) {
            float f[4];
            #pragma unroll
            for (int j = 0; j < 2; ++j) {
                int l = b * 8 + q * 2 + j;
                f32x2 r = level_feat(tables, l, P.n[l], P.fn[l], pt);
                f[j * 2 + 0] = r.x;
                f[j * 2 + 1] = r.y;
            }
            f32x4 v = { f[0], f[1], f[2], f[3] };
            lds[tid * 5 + q] = v;
        }
        __syncthreads();
        #pragma unroll
        for (int i = 0; i < 4; ++i) {
            int e  = i * 256 + tid;
            int pp = e >> 2;
            int q  = e & 3;
            f32x4 v = lds[pp * 5 + q];
            __builtin_nontemporal_store(v, &out[base + pp * 8 + b * 4 + q]);
        }
        __syncthreads();
    }
}

extern "C" void kernel_launch(void* const* d_in, const int* in_sizes, int n_in,
                              void* d_out, int out_size, void* d_ws, size_t ws_size,
                              hipStream_t stream) {
    const f32x2* xy     = (const f32x2*)d_in[0];
    const f32x2* tables = (const f32x2*)d_in[1];
    f32x4* out = (f32x4*)d_out;

    Params P;
    double b = pow(2048.0 / 16.0, 1.0 / 15.0);
    for (int l = 0; l < LVL; ++l) {
        int N = (int)llround(16.0 * pow(b, (double)l));
        P.n[l]  = N;
        P.fn[l] = (float)N;
    }

    // ws: M 1MiB @0 | aux 1KiB @1MiB | slotsA 32MiB @2MiB | slotsB 32MiB @34MiB
    const size_t WS_NEED = 66u << 20;

    if (ws_size >= WS_NEED) {
        char* w = (char*)d_ws;
        unsigned* M      = (unsigned*)(w);
        unsigned* aux    = (unsigned*)(w + (1u << 20));
        f32x4*    slotsA = (f32x4*)   (w + (2u << 20));
        f32x4*    slotsB = (f32x4*)   (w + (34u << 20));

        hist1_kernel     <<<NB1,           256,        0, stream>>>(xy, M);
        scan_local_kernel<<<NCHUNKS,       SCAN_CHUNK, 0, stream>>>(M, aux);
        scan_aux_kernel  <<<1,             NCHUNKS,    0, stream>>>(aux);
        scatter1_kernel  <<<NB1,           256,        0, stream>>>(xy, M, aux, slotsA);
        fine_kernel      <<<CB,            256,        0, stream>>>(slotsA, M, aux, slotsB);
        main_kernel      <<<NPOINTS / 512, 256,        0, stream>>>(slotsB, tables, out, P);
    } else {
        hashgrid2d_fallback<<<NPOINTS / 256, 256, 0, stream>>>(xy, tables, out, P);
    }
}

// Round 20
// 255.378 us; speedup vs baseline: 1.3148x; 1.3148x over previous
//
#include <hip/hip_runtime.h>
#include <math.h>

#define NPOINTS (1 << 21)
#define LVL 16
#define TSIZE (1 << 19)
#define TMASK (TSIZE - 1)
#define PRIME2 2654435761u

// Morton 512x512 (18-bit key); sort uses only coarse = key>>8 (32x32 bins).
#define GBITS 9
#define GRES (1 << GBITS)
#define SCAN_CHUNK 1024
#define CB 1024                        // coarse bins
#define PPB 8192                       // points per phase-1 block
#define NB1 (NPOINTS / PPB)            // 256 blocks
#define MSIZE (CB * NB1)               // 262144 matrix entries
#define NCHUNKS (MSIZE / SCAN_CHUNK)   // 256

typedef float f32x2 __attribute__((ext_vector_type(2)));
typedef float f32x4 __attribute__((ext_vector_type(4)));

struct Params {
    int   n[LVL];
    float fn[LVL];
};

__device__ __forceinline__ unsigned part1by1(unsigned v) {
    v &= 0xFFFFu;
    v = (v | (v << 8)) & 0x00FF00FFu;
    v = (v | (v << 4)) & 0x0F0F0F0Fu;
    v = (v | (v << 2)) & 0x33333333u;
    v = (v | (v << 1)) & 0x55555555u;
    return v;
}

__device__ __forceinline__ unsigned morton_key(f32x2 pt) {
    int kx = (int)(pt.x * (float)GRES);
    int ky = (int)(pt.y * (float)GRES);
    kx = min(max(kx, 0), GRES - 1);
    ky = min(max(ky, 0), GRES - 1);
    return (part1by1((unsigned)ky) << 1) | part1by1((unsigned)kx);
}

// Plain 4-gather bilinear lookup (bit-identical to reference math).
__device__ __forceinline__ f32x2 level_feat(const f32x2* __restrict__ tables,
                                            int l, int N, float fN, f32x2 pt)
{
    float sx = pt.x * fN;
    float sy = pt.y * fN;
    float fx = floorf(sx);
    float fy = floorf(sy);
    float wx = sx - fx;
    float wy = sy - fy;
    int ix = (int)fx;
    int iy = (int)fy;

    int cx0 = (ix     >= N) ? ix - N     : ix;
    int cx1 = (ix + 1 >= N) ? ix + 1 - N : ix + 1;
    int cy0 = (iy     >= N) ? iy - N     : iy;
    int cy1 = (iy + 1 >= N) ? iy + 1 - N : iy + 1;

    unsigned hy0 = (unsigned)cy0 * PRIME2;
    unsigned hy1 = (unsigned)cy1 * PRIME2;

    const f32x2* tbl = tables + (size_t)l * TSIZE;
    f32x2 c00 = tbl[(int)(((unsigned)cx0 ^ hy0) & TMASK)];
    f32x2 c10 = tbl[(int)(((unsigned)cx1 ^ hy0) & TMASK)];
    f32x2 c01 = tbl[(int)(((unsigned)cx0 ^ hy1) & TMASK)];
    f32x2 c11 = tbl[(int)(((unsigned)cx1 ^ hy1) & TMASK)];

    float omx = 1.0f - wx, omy = 1.0f - wy;
    float f0x = c00.x * omx + c10.x * wx;
    float f0y = c00.y * omx + c10.y * wx;
    float f1x = c01.x * omx + c11.x * wx;
    float f1y = c01.y * omx + c11.y * wx;

    f32x2 r;
    r.x = f0x * omy + f1x * wy;
    r.y = f0y * omy + f1y * wy;
    return r;
}

// ---- Phase A1: per-block coarse histogram -> M[bin][block].
__global__ __launch_bounds__(256) void hist1_kernel(
    const f32x2* __restrict__ xy, unsigned* __restrict__ M)
{
    __shared__ unsigned lh[CB];
    int tid = threadIdx.x, b = blockIdx.x;
    for (int k = tid; k < CB; k += 256) lh[k] = 0;
    __syncthreads();
    int base = b * PPB;
    #pragma unroll
    for (int i = 0; i < PPB / 256; ++i) {
        f32x2 pt = __builtin_nontemporal_load(&xy[base + i * 256 + tid]);
        atomicAdd(&lh[morton_key(pt) >> 8], 1u);
    }
    __syncthreads();
    for (int k = tid; k < CB; k += 256) M[k * NB1 + b] = lh[k];
}

// ---- Scan: exclusive scan of M's 262144 entries (bin, block) order.
__global__ __launch_bounds__(SCAN_CHUNK) void scan_local_kernel(
    unsigned* __restrict__ hist, unsigned* __restrict__ aux)
{
    __shared__ unsigned s[SCAN_CHUNK];
    int t = threadIdx.x;
    int i = blockIdx.x * SCAN_CHUNK + t;
    unsigned v = hist[i];
    s[t] = v;
    __syncthreads();
    #pragma unroll
    for (int o = 1; o < SCAN_CHUNK; o <<= 1) {
        unsigned x = (t >= o) ? s[t - o] : 0u;
        __syncthreads();
        s[t] += x;
        __syncthreads();
    }
    hist[i] = s[t] - v;
    if (t == SCAN_CHUNK - 1) aux[blockIdx.x] = s[t];
}

__global__ __launch_bounds__(NCHUNKS) void scan_aux_kernel(unsigned* __restrict__ aux)
{
    __shared__ unsigned s[NCHUNKS];
    int t = threadIdx.x;
    unsigned v = aux[t];
    s[t] = v;
    __syncthreads();
    #pragma unroll
    for (int o = 1; o < NCHUNKS; o <<= 1) {
        unsigned x = (t >= o) ? s[t - o] : 0u;
        __syncthreads();
        s[t] += x;
        __syncthreads();
    }
    aux[t] = s[t] - v;
}

// ---- Phase A2: aggregated scatter via LDS cursors (coalesced runs).
__global__ __launch_bounds__(256) void scatter1_kernel(
    const f32x2* __restrict__ xy, const unsigned* __restrict__ M,
    const unsigned* __restrict__ aux, f32x4* __restrict__ slotsA)
{
    __shared__ unsigned cur[CB];
    int tid = threadIdx.x, b = blockIdx.x;
    for (int k = tid; k < CB; k += 256) {
        unsigned idx = (unsigned)k * NB1 + b;
        cur[k] = M[idx] + aux[idx >> 10];
    }
    __syncthreads();
    int base = b * PPB;
    #pragma unroll
    for (int i = 0; i < PPB / 256; ++i) {
        int p = base + i * 256 + tid;
        f32x2 pt = __builtin_nontemporal_load(&xy[p]);
        unsigned k = morton_key(pt) >> 8;
        unsigned pos = atomicAdd(&cur[k], 1u);
        f32x4 s = { pt.x, pt.y, __uint_as_float((unsigned)p), 0.0f };
        slotsA[pos] = s;
    }
}

// ---- Main: R17 structure, reading the coarse-sorted slots directly.
// Main is vector-memory ISSUE bound (~82 lane-granules/pt); R17 proved dur
// is insensitive to locality (FETCH 87->48 MB, no change), so the fine sort
// is dropped. XCD-bijective swizzle retained.
__global__ __launch_bounds__(256) void main_kernel(
    const f32x4* __restrict__ slots,
    const f32x2* __restrict__ tables,
    f32x4* __restrict__ out,
    Params P)
{
    int bid = (blockIdx.x & 7) * 1024 + (blockIdx.x >> 3);   // 8192 blocks
    int sp  = bid * 256 + threadIdx.x;
    f32x4 s = __builtin_nontemporal_load(&slots[sp]);
    f32x2 pt = { s.x, s.y };
    unsigned op = __float_as_uint(s.z);
    f32x4* o = out + (size_t)op * 8;

    f32x2 r[8];
    #pragma unroll
    for (int j = 0; j < 8; ++j)
        r[j] = level_feat(tables, j, P.n[j], P.fn[j], pt);
    #pragma unroll
    for (int q = 0; q < 4; ++q) {
        f32x4 v = { r[2 * q].x, r[2 * q].y, r[2 * q + 1].x, r[2 * q + 1].y };
        o[q] = v;
    }
    #pragma unroll
    for (int j = 0; j < 8; ++j)
        r[j] = level_feat(tables, 8 + j, P.n[8 + j], P.fn[8 + j], pt);
    #pragma unroll
    for (int q = 0; q < 4; ++q) {
        f32x4 v = { r[2 * q].x, r[2 * q].y, r[2 * q + 1].x, r[2 * q + 1].y };
        o[4 + q] = v;
    }
}

// ---- Fallback (ws too small): single-pass kernel (~433 us).
__global__ __launch_bounds__(256, 6) void hashgrid2d_fallback(
    const f32x2* __restrict__ xy,
    const f32x2* __restrict__ tables,
    f32x4* __restrict__ out,
    Params P)
{
    __shared__ f32x4 lds[256 * 5];

    int tid = threadIdx.x;
    int p   = blockIdx.x * 256 + tid;

    f32x2 pt = __builtin_nontemporal_load(&xy[p]);
    size_t base = (size_t)blockIdx.x * 2048;

    #pragma unroll
    for (int b = 0; b < 2; ++b) {
        #pragma unroll
        for (int q = 0; q < 4; ++q) {
            float f[4];
            #pragma unroll
            for (int j = 0; j < 2; ++j) {
                int l = b * 8 + q * 2 + j;
                f32x2 r = level_feat(tables, l, P.n[l], P.fn[l], pt);
                f[j * 2 + 0] = r.x;
                f[j * 2 + 1] = r.y;
            }
            f32x4 v = { f[0], f[1], f[2], f[3] };
            lds[tid * 5 + q] = v;
        }
        __syncthreads();
        #pragma unroll
        for (int i = 0; i < 4; ++i) {
            int e  = i * 256 + tid;
            int pp = e >> 2;
            int q  = e & 3;
            f32x4 v = lds[pp * 5 + q];
            __builtin_nontemporal_store(v, &out[base + pp * 8 + b * 4 + q]);
        }
        __syncthreads();
    }
}

extern "C" void kernel_launch(void* const* d_in, const int* in_sizes, int n_in,
                              void* d_out, int out_size, void* d_ws, size_t ws_size,
                              hipStream_t stream) {
    const f32x2* xy     = (const f32x2*)d_in[0];
    const f32x2* tables = (const f32x2*)d_in[1];
    f32x4* out = (f32x4*)d_out;

    Params P;
    double b = pow(2048.0 / 16.0, 1.0 / 15.0);
    for (int l = 0; l < LVL; ++l) {
        int N = (int)llround(16.0 * pow(b, (double)l));
        P.n[l]  = N;
        P.fn[l] = (float)N;
    }

    // ws: M 1MiB @0 | aux 1KiB @1MiB | slotsA 32MiB @2MiB
    const size_t WS_NEED = 34u << 20;

    if (ws_size >= WS_NEED) {
        char* w = (char*)d_ws;
        unsigned* M      = (unsigned*)(w);
        unsigned* aux    = (unsigned*)(w + (1u << 20));
        f32x4*    slotsA = (f32x4*)   (w + (2u << 20));

        hist1_kernel     <<<NB1,           256,        0, stream>>>(xy, M);
        scan_local_kernel<<<NCHUNKS,       SCAN_CHUNK, 0, stream>>>(M, aux);
        scan_aux_kernel  <<<1,             NCHUNKS,    0, stream>>>(aux);
        scatter1_kernel  <<<NB1,           256,        0, stream>>>(xy, M, aux, slotsA);
        main_kernel      <<<NPOINTS / 256, 256,        0, stream>>>(slotsA, tables, out, P);
    } else {
        hashgrid2d_fallback<<<NPOINTS / 256, 256, 0, stream>>>(xy, tables, out, P);
    }
}